// Round 15
// baseline (95.872 us; speedup 1.0000x reference)
//
#include <hip/hip_runtime.h>

#define LRELU(x) ((x) > 0.f ? (x) : 0.01f * (x))

// ws layout (float offsets)
#define H2_OFF    0          // [8][16][512]
#define T1_OFF    65536      // [8][512]
#define T2_OFF    69632      // [8][512]
#define PK_OFF    73728      // [8][2048]
#define PB_OFF    90112      // [8][512]
#define D_OFF     94208      // [8][9][2048]
#define WB_OFF    241664     // [8][128][160]  (144 weff + 4 pb + 12 pad)

// ---------------- kA v3: wave-GEMV (lane-split K, shfl reduce) + D zero ----------------
__global__ __launch_bounds__(256) void kA(const float* __restrict__ style,
    const float* __restrict__ dw1_w, const float* __restrict__ dw1_b,
    const float* __restrict__ pk1_w, const float* __restrict__ pk1_b,
    const float* __restrict__ pb1_w, const float* __restrict__ pb1_b,
    float* __restrict__ h2, float* __restrict__ t1, float* __restrict__ t2,
    float* __restrict__ D) {
  int b = blockIdx.x;
  int tid = threadIdx.x;
  __shared__ float smem[512];
  if (b >= 576) {
    int idx = (b - 576) * 256 + tid;
    float4 z; z.x = 0.f; z.y = 0.f; z.z = 0.f; z.w = 0.f;
    for (int j = idx; j < 36864; j += 16384) ((float4*)D)[j] = z;
    return;
  }
  int wave = tid >> 6, l = tid & 63;
  float sv[8];
  const float* w;
  const float* bv;
  float* outp;
  int cobase;
  if (b < 512) {
    int n = b >> 6; int pix = (b >> 2) & 15; int cq = b & 3;
    const float* sp = style + n * 8192 + pix;
#pragma unroll
    for (int j = 0; j < 8; ++j) sv[j] = sp[(8 * l + j) * 16];
    w = dw1_w; bv = dw1_b;
    cobase = cq * 128 + wave * 32;
    outp = h2 + n * 8192 + pix * 512;
  } else {
    int b2 = b - 512;
    int cq = b2 & 3; int which = (b2 >> 2) & 1; int n = b2 >> 3;
    for (int ci = tid; ci < 512; ci += 256) {
      const float4* r4 = (const float4*)(style + n * 8192 + ci * 16);
      float4 a = r4[0], bb = r4[1], c = r4[2], d = r4[3];
      smem[ci] = (a.x+a.y+a.z+a.w + bb.x+bb.y+bb.z+bb.w + c.x+c.y+c.z+c.w + d.x+d.y+d.z+d.w) * (1.f/16.f);
    }
    __syncthreads();
#pragma unroll
    for (int j = 0; j < 8; ++j) sv[j] = smem[8 * l + j];
    w  = which ? pb1_w : pk1_w;
    bv = which ? pb1_b : pk1_b;
    cobase = cq * 128 + wave * 32;
    outp = (which ? t2 : t1) + n * 512;
  }
  float res = (l < 32) ? bv[cobase + l] : 0.f;
#pragma unroll 8
  for (int j = 0; j < 32; ++j) {
    int co = cobase + j;
    const float4* wr = (const float4*)(w + co * 512 + 8 * l);
    float4 a = wr[0], c = wr[1];
    float v = a.x*sv[0] + a.y*sv[1] + a.z*sv[2] + a.w*sv[3]
            + c.x*sv[4] + c.y*sv[5] + c.z*sv[6] + c.w*sv[7];
    v += __shfl_xor(v, 1);
    v += __shfl_xor(v, 2);
    v += __shfl_xor(v, 4);
    v += __shfl_xor(v, 8);
    v += __shfl_xor(v, 16);
    v += __shfl_xor(v, 32);
    if (l == j) res += v;
  }
  if (l < 32) outp[cobase + l] = LRELU(res);
}

// ---------------- kB v3: LDS-staged dw2 matmul + wave-GEMV pk2/pb2 ----------------
// blocks 0..1023: matmul. kc = b & 63 (k-tile 32), bo = (b>>6)&7, nh = b>>9.
// blocks 1024..1183: pk2/pb2 wave-GEMV. 8n x (16 pk-tiles + 4 pb-tiles) of 128 co.
__global__ __launch_bounds__(256) void kB(const float* __restrict__ h2,
    const float* __restrict__ dw2_w,
    const float* __restrict__ t1, const float* __restrict__ t2,
    const float* __restrict__ pk2_w, const float* __restrict__ pk2_b,
    const float* __restrict__ pb2_w, const float* __restrict__ pb2_b,
    float* __restrict__ D, float* __restrict__ pk, float* __restrict__ pb) {
  __shared__ float smem[9856];  // Wt[256][36] = 9216 | ht[4][8][20] = 640
  int b = blockIdx.x;
  int tid = threadIdx.x;
  if (b < 1024) {
    int kc = b & 63; int bo = (b >> 6) & 7; int nh = b >> 9;
    float* Wt = smem;
    float* ht = smem + 9216;
    // stage ht[nn][ci][pix]: 4n x 8ci x 16pix (tid<128: one float4 each)
    if (tid < 128) {
      int pix = tid & 15; int cq = (tid >> 4) & 1; int nn = tid >> 5;
      const float* src = h2 + (nh * 4 + nn) * 8192 + pix * 512 + kc * 8 + cq * 4;
      float4 v = *(const float4*)src;
      float* dst = &ht[(nn * 8 + cq * 4) * 20 + pix];
      dst[0]  = v.x;
      dst[20] = v.y;
      dst[40] = v.z;
      dst[60] = v.w;
    }
    // stage Wt[row][col]: 256 rows x 32 cols, coalesced
#pragma unroll
    for (int m = 0; m < 8; ++m) {
      int fidx = m * 1024 + tid * 4;
      int row = fidx >> 5; int col = fidx & 31;
      float4 v = *(const float4*)(dw2_w + (size_t)(bo * 256 + row) * 2048 + kc * 32 + col);
      *(float4*)&Wt[row * 36 + col] = v;
    }
    __syncthreads();
    int o2 = bo * 256 + tid;
    float acc[4][9];
#pragma unroll
    for (int nn = 0; nn < 4; ++nn)
#pragma unroll
      for (int p = 0; p < 9; ++p) acc[nn][p] = 0.f;
#pragma unroll
    for (int ci = 0; ci < 8; ++ci) {
      float4 wv = *(const float4*)&Wt[tid * 36 + 4 * ci];
#pragma unroll
      for (int nn = 0; nn < 4; ++nn) {
        const float* hrow = &ht[(nn * 8 + ci) * 20];
        float4 a0 = *(const float4*)(hrow + 0);
        float4 a1 = *(const float4*)(hrow + 4);
        float4 a2 = *(const float4*)(hrow + 8);
        float4 a3 = *(const float4*)(hrow + 12);
        float vv[16];
        vv[0]=a0.x; vv[1]=a0.y; vv[2]=a0.z; vv[3]=a0.w;
        vv[4]=a1.x; vv[5]=a1.y; vv[6]=a1.z; vv[7]=a1.w;
        vv[8]=a2.x; vv[9]=a2.y; vv[10]=a2.z; vv[11]=a2.w;
        vv[12]=a3.x; vv[13]=a3.y; vv[14]=a3.z; vv[15]=a3.w;
#pragma unroll
        for (int p = 0; p < 9; ++p) {
          int r = (p / 3) * 4 + (p % 3);
          acc[nn][p] += wv.x * vv[r] + wv.y * vv[r + 1] + wv.z * vv[r + 4] + wv.w * vv[r + 5];
        }
      }
    }
#pragma unroll
    for (int nn = 0; nn < 4; ++nn)
#pragma unroll
      for (int p = 0; p < 9; ++p)
        atomicAdd(&D[((nh * 4 + nn) * 9 + p) * 2048 + o2], acc[nn][p]);
  } else {
    int b2 = b - 1024;  // 0..159
    int n = b2 / 20; int t20 = b2 % 20;
    bool isPb = t20 >= 16;
    int cobase = (isPb ? (t20 - 16) : t20) * 128;
    float* s = smem;
    const float* src = (isPb ? t2 : t1) + n * 512;
    for (int i = tid; i < 512; i += 256) s[i] = src[i];
    __syncthreads();
    int wave = tid >> 6, l = tid & 63;
    float sv[8];
#pragma unroll
    for (int j = 0; j < 8; ++j) sv[j] = s[8 * l + j];
    const float* w  = isPb ? pb2_w : pk2_w;
    const float* bv = isPb ? pb2_b : pk2_b;
    int cg = cobase + wave * 32;
    float res = (l < 32) ? bv[cg + l] : 0.f;
#pragma unroll 8
    for (int j = 0; j < 32; ++j) {
      int co = cg + j;
      const float4* wr = (const float4*)(w + co * 512 + 8 * l);
      float4 a = wr[0], c = wr[1];
      float v = a.x*sv[0] + a.y*sv[1] + a.z*sv[2] + a.w*sv[3]
              + c.x*sv[4] + c.y*sv[5] + c.z*sv[6] + c.w*sv[7];
      v += __shfl_xor(v, 1);
      v += __shfl_xor(v, 2);
      v += __shfl_xor(v, 4);
      v += __shfl_xor(v, 8);
      v += __shfl_xor(v, 16);
      v += __shfl_xor(v, 32);
      if (l == j) res += v;
    }
    if (l < 32) {
      if (isPb) pb[n * 512 + cg + l] = res;
      else      pk[n * 2048 + cg + l] = res;
    }
  }
}

// ---------------- kW: weff + pb -> wbuf[n][Q][160] ----------------
__global__ __launch_bounds__(256) void kW(const float* __restrict__ D,
    const float* __restrict__ pk, const float* __restrict__ dw2_b,
    const float* __restrict__ pb, float* __restrict__ wbuf) {
  int idx = blockIdx.x * 256 + threadIdx.x;
  if (idx >= 8 * 128 * 160) return;
  int t = idx % 160; int Qn = idx / 160; int Q = Qn & 127; int n = Qn >> 7;
  if (t >= 144) {
    wbuf[idx] = (t < 148) ? pb[n * 512 + Q * 4 + (t - 144)] : 0.f;
    return;
  }
  int o = t & 3; int u = t >> 2; int kx = u % 3; int v = u / 3;
  int i = v & 3; int ky = v >> 2; int p = ky * 3 + kx;
  const float* Dp  = D + (n * 9 + p) * 2048 + 16 * Q;
  const float* pkp = pk + n * 2048 + 16 * Q + 4 * o;
  const float* bp  = dw2_b + 16 * Q;
  float sum = 0.f;
#pragma unroll
  for (int j = 0; j < 4; ++j) sum += pkp[j] * (Dp[4 * j + i] + bp[4 * j + i]);
  wbuf[idx] = sum;
}

// ---------------- kC v9: no-LDS, 4px/thread, shfl halos, natural VGPR ----------------
__global__ __launch_bounds__(256) void kC(const float* __restrict__ x,
    const float* __restrict__ wbuf, float* __restrict__ out) {
  int b = blockIdx.x; int rt = b & 3; int Q = (b >> 2) & 127; int n = b >> 9;
  const float* wb = wbuf + (size_t)(n * 128 + Q) * 160;
  const float* base = x + (size_t)(n * 512 + Q * 4) * 4096;
  int e = threadIdx.x & 15;
  int y = rt * 16 + (threadIdx.x >> 4);
  int x0 = 4 * e;
  int ro[3];
#pragma unroll
  for (int ky = 0; ky < 3; ++ky) {
    int ry = y - 1 + ky;
    ry = ry < 0 ? 1 : (ry > 63 ? 62 : ry);
    ro[ky] = ry * 64;
  }
  float acc[4][4];
#pragma unroll
  for (int o = 0; o < 4; ++o) {
    float bv = wb[144 + o];
#pragma unroll
    for (int px = 0; px < 4; ++px) acc[o][px] = bv;
  }
#pragma unroll
  for (int i = 0; i < 4; ++i) {
    const float* ci = base + i * 4096;
#pragma unroll
    for (int ky = 0; ky < 3; ++ky) {
      float4 v0 = *(const float4*)(ci + ro[ky] + x0);
      float vl = __shfl_up(v0.w, 1, 16);
      float vr = __shfl_down(v0.x, 1, 16);
      if (e == 0)  vl = v0.y;
      if (e == 15) vr = v0.z;
      float va0 = vl, va1 = v0.x, va2 = v0.y, va3 = v0.z, va4 = v0.w, va5 = vr;
#pragma unroll
      for (int kx = 0; kx < 3; ++kx) {
        const float* wp = &wb[((ky * 4 + i) * 3 + kx) * 4];
        float w0 = wp[0], w1 = wp[1], w2 = wp[2], w3 = wp[3];
        float xv0 = kx == 0 ? va0 : (kx == 1 ? va1 : va2);
        float xv1 = kx == 0 ? va1 : (kx == 1 ? va2 : va3);
        float xv2 = kx == 0 ? va2 : (kx == 1 ? va3 : va4);
        float xv3 = kx == 0 ? va3 : (kx == 1 ? va4 : va5);
        acc[0][0] += w0 * xv0; acc[0][1] += w0 * xv1; acc[0][2] += w0 * xv2; acc[0][3] += w0 * xv3;
        acc[1][0] += w1 * xv0; acc[1][1] += w1 * xv1; acc[1][2] += w1 * xv2; acc[1][3] += w1 * xv3;
        acc[2][0] += w2 * xv0; acc[2][1] += w2 * xv1; acc[2][2] += w2 * xv2; acc[2][3] += w2 * xv3;
        acc[3][0] += w3 * xv0; acc[3][1] += w3 * xv1; acc[3][2] += w3 * xv2; acc[3][3] += w3 * xv3;
      }
    }
  }
#pragma unroll
  for (int o = 0; o < 4; ++o) {
    float4 st; st.x = acc[o][0]; st.y = acc[o][1]; st.z = acc[o][2]; st.w = acc[o][3];
    *(float4*)&out[(((size_t)(n * 512 + Q * 4 + o)) * 64 + y) * 64 + x0] = st;
  }
}

extern "C" void kernel_launch(void* const* d_in, const int* in_sizes, int n_in,
                              void* d_out, int out_size, void* d_ws, size_t ws_size,
                              hipStream_t stream) {
  const float* style = (const float*)d_in[0];
  const float* pred  = (const float*)d_in[1];
  const float* dw1_w = (const float*)d_in[2];
  const float* dw1_b = (const float*)d_in[3];
  const float* dw2_w = (const float*)d_in[4];
  const float* dw2_b = (const float*)d_in[5];
  const float* pk1_w = (const float*)d_in[6];
  const float* pk1_b = (const float*)d_in[7];
  const float* pk2_w = (const float*)d_in[8];
  const float* pk2_b = (const float*)d_in[9];
  const float* pb1_w = (const float*)d_in[10];
  const float* pb1_b = (const float*)d_in[11];
  const float* pb2_w = (const float*)d_in[12];
  const float* pb2_b = (const float*)d_in[13];
  float* ws = (float*)d_ws;
  float* h2 = ws + H2_OFF;
  float* t1 = ws + T1_OFF;
  float* t2 = ws + T2_OFF;
  float* pk = ws + PK_OFF;
  float* pb = ws + PB_OFF;
  float* D  = ws + D_OFF;
  float* wb = ws + WB_OFF;
  float* out = (float*)d_out;

  kA<<<640, 256, 0, stream>>>(style, dw1_w, dw1_b, pk1_w, pk1_b, pb1_w, pb1_b, h2, t1, t2, D);
  kB<<<1184, 256, 0, stream>>>(h2, dw2_w, t1, t2, pk2_w, pk2_b, pb2_w, pb2_b, D, pk, pb);
  kW<<<640, 256, 0, stream>>>(D, pk, dw2_b, pb, wb);
  kC<<<4096, 256, 0, stream>>>(pred, wb, out);
}

// Round 16
// 71.416 us; speedup vs baseline: 1.3424x; 1.3424x over previous
//
#include <hip/hip_runtime.h>

#define LRELU(x) ((x) > 0.f ? (x) : 0.01f * (x))

// ws layout (float offsets)
#define H2_OFF    0          // h2t [8][512 co][16 pix]
#define T1_OFF    65536      // [8][512]
#define T2_OFF    69632      // [8][512]
#define PK_OFF    73728      // [8][2048]
#define PB_OFF    90112      // [8][512]
#define WB_OFF    241664     // [8][128][160]
// PART lives in d_out: [16 kc][8 n][9 p][2048 o2] = 2359296 floats (d_out has 16.7M)

// ---------------- kA v4: h (transposed write) + pooled stage 1 ----------------
__global__ __launch_bounds__(256) void kA(const float* __restrict__ style,
    const float* __restrict__ dw1_w, const float* __restrict__ dw1_b,
    const float* __restrict__ pk1_w, const float* __restrict__ pk1_b,
    const float* __restrict__ pb1_w, const float* __restrict__ pb1_b,
    float* __restrict__ h2t, float* __restrict__ t1, float* __restrict__ t2) {
  int b = blockIdx.x;
  int tid = threadIdx.x;
  __shared__ float smem[512];
  int wave = tid >> 6, l = tid & 63;
  float sv[8];
  const float* w;
  const float* bv;
  int cobase;
  if (b < 512) {
    int n = b >> 6; int pix = (b >> 2) & 15; int cq = b & 3;
    const float* sp = style + n * 8192 + pix;
#pragma unroll
    for (int j = 0; j < 8; ++j) sv[j] = sp[(8 * l + j) * 16];
    w = dw1_w; bv = dw1_b;
    cobase = cq * 128 + wave * 32;
    float res = (l < 32) ? bv[cobase + l] : 0.f;
#pragma unroll 8
    for (int j = 0; j < 32; ++j) {
      const float4* wr = (const float4*)(w + (cobase + j) * 512 + 8 * l);
      float4 a = wr[0], c = wr[1];
      float v = a.x*sv[0] + a.y*sv[1] + a.z*sv[2] + a.w*sv[3]
              + c.x*sv[4] + c.y*sv[5] + c.z*sv[6] + c.w*sv[7];
      v += __shfl_xor(v, 1);
      v += __shfl_xor(v, 2);
      v += __shfl_xor(v, 4);
      v += __shfl_xor(v, 8);
      v += __shfl_xor(v, 16);
      v += __shfl_xor(v, 32);
      if (l == j) res += v;
    }
    if (l < 32) h2t[n * 8192 + (cobase + l) * 16 + pix] = LRELU(res);
  } else {
    int b2 = b - 512;
    int cq = b2 & 3; int which = (b2 >> 2) & 1; int n = b2 >> 3;
    for (int ci = tid; ci < 512; ci += 256) {
      const float4* r4 = (const float4*)(style + n * 8192 + ci * 16);
      float4 a = r4[0], bb = r4[1], c = r4[2], d = r4[3];
      smem[ci] = (a.x+a.y+a.z+a.w + bb.x+bb.y+bb.z+bb.w + c.x+c.y+c.z+c.w + d.x+d.y+d.z+d.w) * (1.f/16.f);
    }
    __syncthreads();
#pragma unroll
    for (int j = 0; j < 8; ++j) sv[j] = smem[8 * l + j];
    w  = which ? pb1_w : pk1_w;
    bv = which ? pb1_b : pk1_b;
    cobase = cq * 128 + wave * 32;
    float* outp = (which ? t2 : t1) + n * 512;
    float res = (l < 32) ? bv[cobase + l] : 0.f;
#pragma unroll 8
    for (int j = 0; j < 32; ++j) {
      const float4* wr = (const float4*)(w + (cobase + j) * 512 + 8 * l);
      float4 a = wr[0], c = wr[1];
      float v = a.x*sv[0] + a.y*sv[1] + a.z*sv[2] + a.w*sv[3]
              + c.x*sv[4] + c.y*sv[5] + c.z*sv[6] + c.w*sv[7];
      v += __shfl_xor(v, 1);
      v += __shfl_xor(v, 2);
      v += __shfl_xor(v, 4);
      v += __shfl_xor(v, 8);
      v += __shfl_xor(v, 16);
      v += __shfl_xor(v, 32);
      if (l == j) res += v;
    }
    if (l < 32) outp[cobase + l] = LRELU(res);
  }
}

// ---------------- kB v4: no-atomic split-K dw2 matmul + wave-GEMV pk2/pb2 ----------------
// blocks 0..511: matmul. kc = b&15 (K-chunk 128 = 32 ci), bo = (b>>4)&15 (128-o2), nh = b>>8.
//   256 threads = 128 o2 x 2 n-groups (2 n each). Partials -> PART (in d_out).
// blocks 512..671: pk2/pb2 wave-GEMV.
__global__ __launch_bounds__(256) void kB(const float* __restrict__ h2t,
    const float* __restrict__ dw2_w,
    const float* __restrict__ t1, const float* __restrict__ t2,
    const float* __restrict__ pk2_w, const float* __restrict__ pk2_b,
    const float* __restrict__ pb2_w, const float* __restrict__ pb2_b,
    float* __restrict__ PART, float* __restrict__ pk, float* __restrict__ pb) {
  __shared__ float smem[6784];  // Wt_T[32][132] = 4224 | ht[128][20] = 2560
  int b = blockIdx.x;
  int tid = threadIdx.x;
  if (b < 512) {
    int kc = b & 15; int bo = (b >> 4) & 15; int nh = b >> 8;
    float* Wt = smem;          // [32 k][132] per sub-chunk
    float* ht = smem + 4224;   // [nn*32+ci][20]: 16 pix + pad
    // stage ht once: 128 runs (nn,ci) of 16 floats from h2t (coalesced)
    {
      int run = tid >> 1; int half = tid & 1;  // run = nn*32+ci
      int nn = run >> 5; int ci = run & 31;
      const float* src = h2t + (nh * 4 + nn) * 8192 + (kc * 32 + ci) * 16 + half * 8;
      float4 v0 = *(const float4*)src;
      float4 v1 = *(const float4*)(src + 4);
      float* dst = &ht[run * 20 + half * 8];
      *(float4*)dst = v0;
      *(float4*)(dst + 4) = v1;
    }
    int lane = tid & 127; int nng = tid >> 7;
    float acc[2][9];
#pragma unroll
    for (int nn = 0; nn < 2; ++nn)
#pragma unroll
      for (int p = 0; p < 9; ++p) acc[nn][p] = 0.f;
#pragma unroll 1
    for (int sc = 0; sc < 4; ++sc) {
      __syncthreads();  // protect Wt from previous iteration's readers
      // stage Wt_T[32][132]: 128 o2-rows x 32 k-cols (8 ci), coalesced 128B runs
#pragma unroll
      for (int m = 0; m < 4; ++m) {
        int row = m * 32 + (tid >> 3); int kc4 = tid & 7;
        float4 v = *(const float4*)(dw2_w + (size_t)(bo * 128 + row) * 2048 + kc * 128 + sc * 32 + kc4 * 4);
        Wt[(kc4 * 4 + 0) * 132 + row] = v.x;
        Wt[(kc4 * 4 + 1) * 132 + row] = v.y;
        Wt[(kc4 * 4 + 2) * 132 + row] = v.z;
        Wt[(kc4 * 4 + 3) * 132 + row] = v.w;
      }
      __syncthreads();
#pragma unroll
      for (int cil = 0; cil < 8; ++cil) {
        int ci = sc * 8 + cil;
        float wx = Wt[(cil * 4 + 0) * 132 + lane];
        float wy = Wt[(cil * 4 + 1) * 132 + lane];
        float wz = Wt[(cil * 4 + 2) * 132 + lane];
        float ww = Wt[(cil * 4 + 3) * 132 + lane];
#pragma unroll
        for (int nn = 0; nn < 2; ++nn) {
          const float* hrow = &ht[((nng * 2 + nn) * 32 + ci) * 20];
          float4 a0 = *(const float4*)(hrow + 0);
          float4 a1 = *(const float4*)(hrow + 4);
          float4 a2 = *(const float4*)(hrow + 8);
          float4 a3 = *(const float4*)(hrow + 12);
          float vv[16];
          vv[0]=a0.x; vv[1]=a0.y; vv[2]=a0.z; vv[3]=a0.w;
          vv[4]=a1.x; vv[5]=a1.y; vv[6]=a1.z; vv[7]=a1.w;
          vv[8]=a2.x; vv[9]=a2.y; vv[10]=a2.z; vv[11]=a2.w;
          vv[12]=a3.x; vv[13]=a3.y; vv[14]=a3.z; vv[15]=a3.w;
#pragma unroll
          for (int p = 0; p < 9; ++p) {
            int r = (p / 3) * 4 + (p % 3);
            acc[nn][p] += wx * vv[r] + wy * vv[r + 1] + wz * vv[r + 4] + ww * vv[r + 5];
          }
        }
      }
    }
    // store partials: coalesced in o2
#pragma unroll
    for (int nn = 0; nn < 2; ++nn) {
      int n = nh * 4 + nng * 2 + nn;
#pragma unroll
      for (int p = 0; p < 9; ++p)
        PART[(size_t)kc * 147456 + ((n * 9 + p) * 2048) + bo * 128 + lane] = acc[nn][p];
    }
  } else {
    int b2 = b - 512;  // 0..159
    int n = b2 / 20; int t20 = b2 % 20;
    bool isPb = t20 >= 16;
    int cobase = (isPb ? (t20 - 16) : t20) * 128;
    float* s = smem;
    const float* src = (isPb ? t2 : t1) + n * 512;
    for (int i = tid; i < 512; i += 256) s[i] = src[i];
    __syncthreads();
    int wave = tid >> 6, l = tid & 63;
    float sv[8];
#pragma unroll
    for (int j = 0; j < 8; ++j) sv[j] = s[8 * l + j];
    const float* w  = isPb ? pb2_w : pk2_w;
    const float* bv = isPb ? pb2_b : pk2_b;
    int cg = cobase + wave * 32;
    float res = (l < 32) ? bv[cg + l] : 0.f;
#pragma unroll 8
    for (int j = 0; j < 32; ++j) {
      const float4* wr = (const float4*)(w + (cg + j) * 512 + 8 * l);
      float4 a = wr[0], c = wr[1];
      float v = a.x*sv[0] + a.y*sv[1] + a.z*sv[2] + a.w*sv[3]
              + c.x*sv[4] + c.y*sv[5] + c.z*sv[6] + c.w*sv[7];
      v += __shfl_xor(v, 1);
      v += __shfl_xor(v, 2);
      v += __shfl_xor(v, 4);
      v += __shfl_xor(v, 8);
      v += __shfl_xor(v, 16);
      v += __shfl_xor(v, 32);
      if (l == j) res += v;
    }
    if (l < 32) {
      if (isPb) pb[n * 512 + cg + l] = res;
      else      pk[n * 2048 + cg + l] = res;
    }
  }
}

// ---------------- kW v2: weff + pb -> wbuf; sums 16 PART slices inline ----------------
__global__ __launch_bounds__(256) void kW(const float* __restrict__ PART,
    const float* __restrict__ pk, const float* __restrict__ dw2_b,
    const float* __restrict__ pb, float* __restrict__ wbuf) {
  int idx = blockIdx.x * 256 + threadIdx.x;
  if (idx >= 8 * 128 * 160) return;
  int t = idx % 160; int Qn = idx / 160; int Q = Qn & 127; int n = Qn >> 7;
  if (t >= 144) {
    wbuf[idx] = (t < 148) ? pb[n * 512 + Q * 4 + (t - 144)] : 0.f;
    return;
  }
  int o = t & 3; int u = t >> 2; int kx = u % 3; int v = u / 3;
  int i = v & 3; int ky = v >> 2; int p = ky * 3 + kx;
  const float* pkp = pk + n * 2048 + 16 * Q + 4 * o;
  const float* bp  = dw2_b + 16 * Q;
  size_t dbase = (size_t)(n * 9 + p) * 2048 + 16 * Q;
  float sum = 0.f;
#pragma unroll
  for (int j = 0; j < 4; ++j) {
    float dv = bp[4 * j + i];
    size_t off = dbase + 4 * j + i;
#pragma unroll
    for (int s = 0; s < 16; ++s) dv += PART[(size_t)s * 147456 + off];
    sum += pkp[j] * dv;
  }
  wbuf[idx] = sum;
}

// ---------------- kC v9: no-LDS, 4px/thread, shfl halos, natural VGPR ----------------
__global__ __launch_bounds__(256) void kC(const float* __restrict__ x,
    const float* __restrict__ wbuf, float* __restrict__ out) {
  int b = blockIdx.x; int rt = b & 3; int Q = (b >> 2) & 127; int n = b >> 9;
  const float* wb = wbuf + (size_t)(n * 128 + Q) * 160;
  const float* base = x + (size_t)(n * 512 + Q * 4) * 4096;
  int e = threadIdx.x & 15;
  int y = rt * 16 + (threadIdx.x >> 4);
  int x0 = 4 * e;
  int ro[3];
#pragma unroll
  for (int ky = 0; ky < 3; ++ky) {
    int ry = y - 1 + ky;
    ry = ry < 0 ? 1 : (ry > 63 ? 62 : ry);
    ro[ky] = ry * 64;
  }
  float acc[4][4];
#pragma unroll
  for (int o = 0; o < 4; ++o) {
    float bv = wb[144 + o];
#pragma unroll
    for (int px = 0; px < 4; ++px) acc[o][px] = bv;
  }
#pragma unroll
  for (int i = 0; i < 4; ++i) {
    const float* ci = base + i * 4096;
#pragma unroll
    for (int ky = 0; ky < 3; ++ky) {
      float4 v0 = *(const float4*)(ci + ro[ky] + x0);
      float vl = __shfl_up(v0.w, 1, 16);
      float vr = __shfl_down(v0.x, 1, 16);
      if (e == 0)  vl = v0.y;
      if (e == 15) vr = v0.z;
      float va0 = vl, va1 = v0.x, va2 = v0.y, va3 = v0.z, va4 = v0.w, va5 = vr;
#pragma unroll
      for (int kx = 0; kx < 3; ++kx) {
        const float* wp = &wb[((ky * 4 + i) * 3 + kx) * 4];
        float w0 = wp[0], w1 = wp[1], w2 = wp[2], w3 = wp[3];
        float xv0 = kx == 0 ? va0 : (kx == 1 ? va1 : va2);
        float xv1 = kx == 0 ? va1 : (kx == 1 ? va2 : va3);
        float xv2 = kx == 0 ? va2 : (kx == 1 ? va3 : va4);
        float xv3 = kx == 0 ? va3 : (kx == 1 ? va4 : va5);
        acc[0][0] += w0 * xv0; acc[0][1] += w0 * xv1; acc[0][2] += w0 * xv2; acc[0][3] += w0 * xv3;
        acc[1][0] += w1 * xv0; acc[1][1] += w1 * xv1; acc[1][2] += w1 * xv2; acc[1][3] += w1 * xv3;
        acc[2][0] += w2 * xv0; acc[2][1] += w2 * xv1; acc[2][2] += w2 * xv2; acc[2][3] += w2 * xv3;
        acc[3][0] += w3 * xv0; acc[3][1] += w3 * xv1; acc[3][2] += w3 * xv2; acc[3][3] += w3 * xv3;
      }
    }
  }
#pragma unroll
  for (int o = 0; o < 4; ++o) {
    float4 st; st.x = acc[o][0]; st.y = acc[o][1]; st.z = acc[o][2]; st.w = acc[o][3];
    *(float4*)&out[(((size_t)(n * 512 + Q * 4 + o)) * 64 + y) * 64 + x0] = st;
  }
}

extern "C" void kernel_launch(void* const* d_in, const int* in_sizes, int n_in,
                              void* d_out, int out_size, void* d_ws, size_t ws_size,
                              hipStream_t stream) {
  const float* style = (const float*)d_in[0];
  const float* pred  = (const float*)d_in[1];
  const float* dw1_w = (const float*)d_in[2];
  const float* dw1_b = (const float*)d_in[3];
  const float* dw2_w = (const float*)d_in[4];
  const float* dw2_b = (const float*)d_in[5];
  const float* pk1_w = (const float*)d_in[6];
  const float* pk1_b = (const float*)d_in[7];
  const float* pk2_w = (const float*)d_in[8];
  const float* pk2_b = (const float*)d_in[9];
  const float* pb1_w = (const float*)d_in[10];
  const float* pb1_b = (const float*)d_in[11];
  const float* pb2_w = (const float*)d_in[12];
  const float* pb2_b = (const float*)d_in[13];
  float* ws  = (float*)d_ws;
  float* h2t = ws + H2_OFF;
  float* t1  = ws + T1_OFF;
  float* t2  = ws + T2_OFF;
  float* pk  = ws + PK_OFF;
  float* pb  = ws + PB_OFF;
  float* wb  = ws + WB_OFF;
  float* out = (float*)d_out;
  float* PART = out;  // scratch in d_out; fully overwritten by kC afterwards

  kA<<<576, 256, 0, stream>>>(style, dw1_w, dw1_b, pk1_w, pk1_b, pb1_w, pb1_b, h2t, t1, t2);
  kB<<<672, 256, 0, stream>>>(h2t, dw2_w, t1, t2, pk2_w, pk2_b, pb2_w, pb2_b, PART, pk, pb);
  kW<<<640, 256, 0, stream>>>(PART, pk, dw2_b, pb, wb);
  kC<<<4096, 256, 0, stream>>>(pred, wb, out);
}